// Round 1
// baseline (303.155 us; speedup 1.0000x reference)
//
#include <hip/hip_runtime.h>

typedef unsigned short u16;
typedef __attribute__((ext_vector_type(4))) float f32x4;
typedef __attribute__((ext_vector_type(8))) __bf16 bf16x8;

#define L2E 1.4426950408889634f

__device__ __forceinline__ u16 f2bf(float f) {
  unsigned u = __builtin_bit_cast(unsigned, f);
  u += 0x7FFFu + ((u >> 16) & 1u);
  return (u16)(u >> 16);
}
__device__ __forceinline__ float bf2f(u16 h) {
  unsigned u = ((unsigned)h) << 16;
  return __builtin_bit_cast(float, u);
}
__device__ __forceinline__ f32x4 mfma16(bf16x8 a, bf16x8 b, f32x4 c) {
  return __builtin_amdgcn_mfma_f32_16x16x32_bf16(a, b, c, 0, 0, 0);
}
__device__ __forceinline__ void gl_lds16(const u16* g, u16* l) {
  __builtin_amdgcn_global_load_lds((__attribute__((address_space(1))) void*)g,
                                   (__attribute__((address_space(3))) void*)l,
                                   16, 0, 0);
}
__device__ __forceinline__ f32x4 fzero() {
  f32x4 v = {0.f, 0.f, 0.f, 0.f};
  return v;
}

// ---------------- converters ----------------
__global__ void k_split(const float* __restrict__ src, u16* __restrict__ hi,
                        u16* __restrict__ lo, int n) {
  int i = (blockIdx.x * 256 + threadIdx.x) * 4;
  if (i >= n) return;
  float4 v = *(const float4*)(src + i);
  float vv[4] = {v.x, v.y, v.z, v.w};
#pragma unroll
  for (int j = 0; j < 4; ++j) {
    u16 h = f2bf(vv[j]);
    hi[i + j] = h;
    lo[i + j] = f2bf(vv[j] - bf2f(h));
  }
}

__global__ void k_cvt(const float* __restrict__ src, u16* __restrict__ dst, int n) {
  int i = (blockIdx.x * 256 + threadIdx.x) * 4;
  if (i >= n) return;
  float4 v = *(const float4*)(src + i);
  float vv[4] = {v.x, v.y, v.z, v.w};
#pragma unroll
  for (int j = 0; j < 4; ++j) dst[i + j] = f2bf(vv[j]);
}

// ---------------- GEMM: C[4096][1024] = A[4096][1024] * B[1024][1024]^T + bias ----------------
// SPLIT=1: A,B given as hi/lo bf16 pairs; 3-MFMA high-precision product.
// EPI=0: split-store to [b][h][s][64] hi/lo (Q,K).  EPI=1: bf16 store transposed
// [b][h][64][s] (V).  EPI=2: f32 store [n][1024] (final output).
template <int SPLIT, int EPI>
__global__ __launch_bounds__(256) void k_gemm(
    const u16* __restrict__ Ah, const u16* __restrict__ Al,
    const u16* __restrict__ Bh, const u16* __restrict__ Bl,
    const float* __restrict__ bias, u16* __restrict__ oH, u16* __restrict__ oL,
    float* __restrict__ oF) {
  __shared__ u16 sm[(SPLIT ? 4 : 2) * 4096];
  u16* sAh = sm;
  u16* sBh = sm + 4096;
  u16* sAl = SPLIT ? (sm + 8192) : sm;
  u16* sBl = SPLIT ? (sm + 12288) : sm;

  const int tid = threadIdx.x;
  const int lane = tid & 63, w = tid >> 6;
  const int wm = w >> 1, wn = w & 1;
  const int fr = lane & 15, fg = lane >> 4;
  const int m0 = blockIdx.x * 128, n0 = blockIdx.y * 128;
  const int srow = tid >> 2, scb = (tid & 3) * 8;

  f32x4 acc[4][4];
#pragma unroll
  for (int i = 0; i < 4; ++i)
#pragma unroll
    for (int j = 0; j < 4; ++j) acc[i][j] = fzero();

  for (int kk = 0; kk < 1024; kk += 32) {
    __syncthreads();
#pragma unroll
    for (int r = 0; r < 2; ++r) {
      int row = r * 64 + srow;
      gl_lds16(Ah + (size_t)(m0 + row) * 1024 + kk + scb, sAh + row * 32 + scb);
      gl_lds16(Bh + (size_t)(n0 + row) * 1024 + kk + scb, sBh + row * 32 + scb);
      if constexpr (SPLIT) {
        gl_lds16(Al + (size_t)(m0 + row) * 1024 + kk + scb, sAl + row * 32 + scb);
        gl_lds16(Bl + (size_t)(n0 + row) * 1024 + kk + scb, sBl + row * 32 + scb);
      }
    }
    __syncthreads();

    bf16x8 ah[4], bh[4], al[4], bl[4];
#pragma unroll
    for (int i = 0; i < 4; ++i) {
      ah[i] = *(const bf16x8*)(sAh + (wm * 64 + i * 16 + fr) * 32 + fg * 8);
      bh[i] = *(const bf16x8*)(sBh + (wn * 64 + i * 16 + fr) * 32 + fg * 8);
      if constexpr (SPLIT) {
        al[i] = *(const bf16x8*)(sAl + (wm * 64 + i * 16 + fr) * 32 + fg * 8);
        bl[i] = *(const bf16x8*)(sBl + (wn * 64 + i * 16 + fr) * 32 + fg * 8);
      }
    }
#pragma unroll
    for (int i = 0; i < 4; ++i)
#pragma unroll
      for (int j = 0; j < 4; ++j) {
        acc[i][j] = mfma16(ah[i], bh[j], acc[i][j]);
        if constexpr (SPLIT) {
          acc[i][j] = mfma16(ah[i], bl[j], acc[i][j]);
          acc[i][j] = mfma16(al[i], bh[j], acc[i][j]);
        }
      }
  }

  // epilogue: C/D layout col = lane&15, row = (lane>>4)*4 + r  [m89/m91 verified]
#pragma unroll
  for (int i = 0; i < 4; ++i)
#pragma unroll
    for (int j = 0; j < 4; ++j) {
      int cg = n0 + wn * 64 + j * 16 + fr;
      float bv = bias[cg];
#pragma unroll
      for (int r = 0; r < 4; ++r) {
        int rg = m0 + wm * 64 + i * 16 + fg * 4 + r;
        float val = acc[i][j][r] + bv;
        if constexpr (EPI == 0) {
          int b = rg >> 11, s = rg & 2047, hh = cg >> 6, d = cg & 63;
          size_t off = ((size_t)((b * 16 + hh) * 2048 + s)) * 64 + d;
          u16 hi = f2bf(val);
          oH[off] = hi;
          oL[off] = f2bf(val - bf2f(hi));
        } else if constexpr (EPI == 1) {
          int b = rg >> 11, s = rg & 2047, hh = cg >> 6, d = cg & 63;
          size_t off = ((size_t)((b * 16 + hh) * 64 + d)) * 2048 + s;
          oH[off] = f2bf(val);
        } else {
          oF[(size_t)rg * 1024 + cg] = val;
        }
      }
    }
}

// ---------------- flash attention (causal) ----------------
// Q,K: [b][h][2048][64] as hi/lo bf16 pairs.  Vt: [b][h][64][2048] bf16.
// Out: attn bf16 [n=4096][1024].
__global__ __launch_bounds__(256) void k_attn(
    const u16* __restrict__ Qh, const u16* __restrict__ Ql,
    const u16* __restrict__ Kh, const u16* __restrict__ Kl,
    const u16* __restrict__ Vt, u16* __restrict__ Oa) {
  __shared__ u16 sKh[4096];  // [64 kv][64 d], XOR-swizzled 16B blocks
  __shared__ u16 sKl[4096];
  __shared__ u16 sVt[4096];  // [64 d][64 kv], XOR-swizzled
  __shared__ u16 sP[4][1024];  // per-wave [16 q][64 kv], XOR-swizzled

  const int tid = threadIdx.x;
  const int lane = tid & 63, w = tid >> 6;
  const int fr = lane & 15, fg = lane >> 4;
  const int qt = blockIdx.x, bh = blockIdx.y;
  const size_t base = (size_t)bh * 131072;  // 2048*64
  const u16* Qh_p = Qh + base;
  const u16* Ql_p = Ql + base;
  const u16* Kh_p = Kh + base;
  const u16* Kl_p = Kl + base;
  const u16* Vt_p = Vt + base;

  // Q fragments in registers: wave w owns q rows qt*64 + w*16 .. +15
  const int qrow = qt * 64 + w * 16 + fr;
  bf16x8 qhf[2], qlf[2];
#pragma unroll
  for (int ks = 0; ks < 2; ++ks) {
    qhf[ks] = *(const bf16x8*)(Qh_p + (size_t)qrow * 64 + ks * 32 + fg * 8);
    qlf[ks] = *(const bf16x8*)(Ql_p + (size_t)qrow * 64 + ks * 32 + fg * 8);
  }

  float m[4], l[4];
  f32x4 o[4];
#pragma unroll
  for (int r = 0; r < 4; ++r) { m[r] = -1e30f; l[r] = 0.f; }
#pragma unroll
  for (int f = 0; f < 4; ++f) o[f] = fzero();

  const int srow = tid >> 3, scb = tid & 7;

  for (int t = 0; t <= qt; ++t) {
    __syncthreads();
    // stage K_hi, K_lo, V^T tiles; source pre-swizzled so swizzled reads work
#pragma unroll
    for (int r2 = 0; r2 < 2; ++r2) {
      int row = r2 * 32 + srow;
      int cbs = scb ^ (row & 7);
      gl_lds16(Kh_p + (size_t)(t * 64 + row) * 64 + cbs * 8, sKh + row * 64 + scb * 8);
      gl_lds16(Kl_p + (size_t)(t * 64 + row) * 64 + cbs * 8, sKl + row * 64 + scb * 8);
      gl_lds16(Vt_p + (size_t)row * 2048 + t * 64 + cbs * 8, sVt + row * 64 + scb * 8);
    }
    __syncthreads();

    // scores: S[q][kv] = (qh+ql)·(kh+kl)/8, 3-MFMA split product
    f32x4 sc[4];
#pragma unroll
    for (int f = 0; f < 4; ++f) {
      f32x4 a = fzero();
#pragma unroll
      for (int ks = 0; ks < 2; ++ks) {
        int row = f * 16 + fr;
        int cb = (fg + 4 * ks) ^ (row & 7);
        bf16x8 kh = *(const bf16x8*)(sKh + row * 64 + cb * 8);
        bf16x8 kl = *(const bf16x8*)(sKl + row * 64 + cb * 8);
        a = mfma16(qhf[ks], kh, a);
        a = mfma16(qhf[ks], kl, a);
        a = mfma16(qlf[ks], kh, a);
      }
      sc[f] = a * 0.125f;
    }

    if (t == qt) {  // causal mask on the diagonal tile
#pragma unroll
      for (int f = 0; f < 4; ++f) {
        int kvl = f * 16 + fr;
#pragma unroll
        for (int r = 0; r < 4; ++r) {
          int qq = w * 16 + fg * 4 + r;
          if (kvl > qq) sc[f][r] = -1e30f;
        }
      }
    }

    // online softmax; row = fg*4 + r, replicated across 16 lanes (fr)
    float pm[4];
#pragma unroll
    for (int r = 0; r < 4; ++r)
      pm[r] = fmaxf(fmaxf(sc[0][r], sc[1][r]), fmaxf(sc[2][r], sc[3][r]));
#pragma unroll
    for (int d = 1; d < 16; d <<= 1)
#pragma unroll
      for (int r = 0; r < 4; ++r) pm[r] = fmaxf(pm[r], __shfl_xor(pm[r], d, 64));

    float alp[4], ps[4];
#pragma unroll
    for (int r = 0; r < 4; ++r) {
      float mn = fmaxf(m[r], pm[r]);
      alp[r] = exp2f((m[r] - mn) * L2E);
      m[r] = mn;
      ps[r] = 0.f;
    }
#pragma unroll
    for (int f = 0; f < 4; ++f)
#pragma unroll
      for (int r = 0; r < 4; ++r) {
        float p = exp2f((sc[f][r] - m[r]) * L2E);
        ps[r] += p;
        int row = fg * 4 + r;
        int c = f * 16 + fr;
        sP[w][row * 64 + (c ^ ((row & 7) << 3))] = f2bf(p);
      }
#pragma unroll
    for (int d = 1; d < 16; d <<= 1)
#pragma unroll
      for (int r = 0; r < 4; ++r) ps[r] += __shfl_xor(ps[r], d, 64);
#pragma unroll
    for (int r = 0; r < 4; ++r) l[r] = l[r] * alp[r] + ps[r];
#pragma unroll
    for (int f = 0; f < 4; ++f)
#pragma unroll
      for (int r = 0; r < 4; ++r) o[f][r] *= alp[r];

    // PV: out[q][d] += P[q][kv] * V[kv][d]
#pragma unroll
    for (int ks = 0; ks < 2; ++ks) {
      int c0 = fg * 8 + ks * 32;
      bf16x8 pa = *(const bf16x8*)(&sP[w][fr * 64 + (c0 ^ ((fr & 7) << 3))]);
#pragma unroll
      for (int f = 0; f < 4; ++f) {
        int row = f * 16 + fr;
        int cb = (fg + 4 * ks) ^ (row & 7);
        bf16x8 vb = *(const bf16x8*)(sVt + row * 64 + cb * 8);
        o[f] = mfma16(pa, vb, o[f]);
      }
    }
  }

  // epilogue → attn bf16 [n][1024]
  int b = bh >> 4, h = bh & 15;
#pragma unroll
  for (int f = 0; f < 4; ++f)
#pragma unroll
    for (int r = 0; r < 4; ++r) {
      int qg = qt * 64 + w * 16 + fg * 4 + r;
      float val = o[f][r] / l[r];
      Oa[((size_t)(b * 2048 + qg)) * 1024 + h * 64 + f * 16 + fr] = f2bf(val);
    }
}

// ---------------- launcher ----------------
extern "C" void kernel_launch(void* const* d_in, const int* in_sizes, int n_in,
                              void* d_out, int out_size, void* d_ws, size_t ws_size,
                              hipStream_t stream) {
  const float* x  = (const float*)d_in[0];
  const float* Wq = (const float*)d_in[1];
  const float* bq = (const float*)d_in[2];
  const float* Wk = (const float*)d_in[3];
  const float* bk = (const float*)d_in[4];
  const float* Wv = (const float*)d_in[5];
  const float* bv = (const float*)d_in[6];
  const float* Wo = (const float*)d_in[7];
  const float* bo = (const float*)d_in[8];
  float* out = (float*)d_out;

  u16* ws  = (u16*)d_ws;
  u16* xh  = ws;
  u16* xl  = xh + 4194304;
  u16* wqh = xl + 4194304;
  u16* wql = wqh + 1048576;
  u16* wkh = wql + 1048576;
  u16* wkl = wkh + 1048576;
  u16* wvb = wkl + 1048576;
  u16* wob = wvb + 1048576;
  u16* qh  = wob + 1048576;
  u16* ql  = qh + 4194304;
  u16* kh  = ql + 4194304;
  u16* kl  = kh + 4194304;
  u16* vt  = kl + 4194304;
  u16* ao  = xh;  // x_hi dead after projections; reuse for attention output

  k_split<<<4096, 256, 0, stream>>>(x, xh, xl, 4194304);
  k_split<<<1024, 256, 0, stream>>>(Wq, wqh, wql, 1048576);
  k_split<<<1024, 256, 0, stream>>>(Wk, wkh, wkl, 1048576);
  k_cvt<<<1024, 256, 0, stream>>>(Wv, wvb, 1048576);
  k_cvt<<<1024, 256, 0, stream>>>(Wo, wob, 1048576);

  k_gemm<1, 0><<<dim3(32, 8), 256, 0, stream>>>(xh, xl, wqh, wql, bq, qh, ql, nullptr);
  k_gemm<1, 0><<<dim3(32, 8), 256, 0, stream>>>(xh, xl, wkh, wkl, bk, kh, kl, nullptr);
  k_gemm<0, 1><<<dim3(32, 8), 256, 0, stream>>>(xh, nullptr, wvb, nullptr, bv, vt, nullptr, nullptr);

  k_attn<<<dim3(32, 32), 256, 0, stream>>>(qh, ql, kh, kl, vt, ao);

  k_gemm<0, 2><<<dim3(32, 8), 256, 0, stream>>>(ao, nullptr, wob, nullptr, bo, nullptr, nullptr, out);
}

// Round 2
// 188.528 us; speedup vs baseline: 1.6080x; 1.6080x over previous
//
#include <hip/hip_runtime.h>

typedef unsigned short u16;
typedef unsigned int u32;
typedef __attribute__((ext_vector_type(4))) float f32x4;
typedef __attribute__((ext_vector_type(8))) __bf16 bf16x8;

#define L2E 1.4426950408889634f

__device__ __forceinline__ u16 f2bf(float f) { return __builtin_bit_cast(u16, (__bf16)f); }
__device__ __forceinline__ float bf2f(u16 h) { return (float)__builtin_bit_cast(__bf16, h); }
__device__ __forceinline__ f32x4 mfma16(bf16x8 a, bf16x8 b, f32x4 c) {
  return __builtin_amdgcn_mfma_f32_16x16x32_bf16(a, b, c, 0, 0, 0);
}
__device__ __forceinline__ void gl_lds16(const u16* g, u16* l) {
  __builtin_amdgcn_global_load_lds((__attribute__((address_space(1))) void*)g,
                                   (__attribute__((address_space(3))) void*)l,
                                   16, 0, 0);
}
__device__ __forceinline__ f32x4 fzero() {
  f32x4 v = {0.f, 0.f, 0.f, 0.f};
  return v;
}

// ---------------- fused prep: x hi/lo split, Wq/Wk splits, Wv/Wo converts ----------------
__global__ void k_prep(const float* __restrict__ x, const float* __restrict__ Wq,
                       const float* __restrict__ Wk, const float* __restrict__ Wv,
                       const float* __restrict__ Wo,
                       u16* __restrict__ xh, u16* __restrict__ xl,
                       u16* __restrict__ wqh, u16* __restrict__ wql,
                       u16* __restrict__ wkh, u16* __restrict__ wkl,
                       u16* __restrict__ wvb, u16* __restrict__ wob) {
  int i = (blockIdx.x * 256 + threadIdx.x) * 4;
  const float* src;
  u16* hi;
  u16* lo;
  int j;
  if (i < 4194304)      { src = x;  hi = xh;  lo = xl;      j = i; }
  else if (i < 5242880) { src = Wq; hi = wqh; lo = wql;     j = i - 4194304; }
  else if (i < 6291456) { src = Wk; hi = wkh; lo = wkl;     j = i - 5242880; }
  else if (i < 7340032) { src = Wv; hi = wvb; lo = nullptr; j = i - 6291456; }
  else                  { src = Wo; hi = wob; lo = nullptr; j = i - 7340032; }
  float4 v = *(const float4*)(src + j);
  float vv[4] = {v.x, v.y, v.z, v.w};
  u16 hh[4];
#pragma unroll
  for (int t = 0; t < 4; ++t) hh[t] = f2bf(vv[t]);
  *(ushort4*)(hi + j) = make_ushort4(hh[0], hh[1], hh[2], hh[3]);
  if (lo) {
    u16 ll[4];
#pragma unroll
    for (int t = 0; t < 4; ++t) ll[t] = f2bf(vv[t] - bf2f(hh[t]));
    *(ushort4*)(lo + j) = make_ushort4(ll[0], ll[1], ll[2], ll[3]);
  }
}

// ---------------- GEMM body: C[.][1024] = A[.][1024] * B[1024][1024]^T + bias ----------------
// SPLIT=1: 3-MFMA hi/lo high-precision product.
// EPI=0: split-store (val*scale) to [b][h][s][64] hi/lo.  EPI=1: bf16 transposed
// [b][h][64][s].  EPI=2: f32 [rg][1024].
template <int SPLIT, int EPI>
__device__ __forceinline__ void gemm_body(
    u16* sm, const u16* __restrict__ Ah, const u16* __restrict__ Al,
    const u16* __restrict__ Bh, const u16* __restrict__ Bl,
    const float* __restrict__ bias, float scale,
    u16* __restrict__ oH, u16* __restrict__ oL, float* __restrict__ oF,
    int m0, int n0) {
  u16* sAh = sm;
  u16* sBh = sm + 4096;
  u16* sAl = SPLIT ? (sm + 8192) : sm;
  u16* sBl = SPLIT ? (sm + 12288) : sm;

  const int tid = threadIdx.x;
  const int lane = tid & 63, w = tid >> 6;
  const int wm = w >> 1, wn = w & 1;
  const int fr = lane & 15, fg = lane >> 4;
  const int srow = tid >> 2, scb = (tid & 3) * 8;

  f32x4 acc[4][4];
#pragma unroll
  for (int i = 0; i < 4; ++i)
#pragma unroll
    for (int j = 0; j < 4; ++j) acc[i][j] = fzero();

  for (int kk = 0; kk < 1024; kk += 32) {
    __syncthreads();
#pragma unroll
    for (int r = 0; r < 2; ++r) {
      int row = r * 64 + srow;
      gl_lds16(Ah + (size_t)(m0 + row) * 1024 + kk + scb, sAh + row * 32 + scb);
      gl_lds16(Bh + (size_t)(n0 + row) * 1024 + kk + scb, sBh + row * 32 + scb);
      if constexpr (SPLIT) {
        gl_lds16(Al + (size_t)(m0 + row) * 1024 + kk + scb, sAl + row * 32 + scb);
        gl_lds16(Bl + (size_t)(n0 + row) * 1024 + kk + scb, sBl + row * 32 + scb);
      }
    }
    __syncthreads();

    bf16x8 ah[4], bh[4], al[4], bl[4];
#pragma unroll
    for (int i = 0; i < 4; ++i) {
      ah[i] = *(const bf16x8*)(sAh + (wm * 64 + i * 16 + fr) * 32 + fg * 8);
      bh[i] = *(const bf16x8*)(sBh + (wn * 64 + i * 16 + fr) * 32 + fg * 8);
      if constexpr (SPLIT) {
        al[i] = *(const bf16x8*)(sAl + (wm * 64 + i * 16 + fr) * 32 + fg * 8);
        bl[i] = *(const bf16x8*)(sBl + (wn * 64 + i * 16 + fr) * 32 + fg * 8);
      }
    }
#pragma unroll
    for (int i = 0; i < 4; ++i)
#pragma unroll
      for (int j = 0; j < 4; ++j) {
        acc[i][j] = mfma16(ah[i], bh[j], acc[i][j]);
        if constexpr (SPLIT) {
          acc[i][j] = mfma16(ah[i], bl[j], acc[i][j]);
          acc[i][j] = mfma16(al[i], bh[j], acc[i][j]);
        }
      }
  }

  // C/D layout: col = lane&15, row = (lane>>4)*4 + r
#pragma unroll
  for (int i = 0; i < 4; ++i)
#pragma unroll
    for (int j = 0; j < 4; ++j) {
      int cg = n0 + wn * 64 + j * 16 + fr;
      float bv = bias[cg];
#pragma unroll
      for (int r = 0; r < 4; ++r) {
        int rg = m0 + wm * 64 + i * 16 + fg * 4 + r;
        float val = (acc[i][j][r] + bv) * scale;
        if constexpr (EPI == 0) {
          int b = rg >> 11, s = rg & 2047, hd2 = cg >> 6, dd = cg & 63;
          size_t off = ((size_t)((b * 16 + hd2) * 2048 + s)) * 64 + dd;
          u16 hv = f2bf(val);
          oH[off] = hv;
          oL[off] = f2bf(val - bf2f(hv));
        } else if constexpr (EPI == 1) {
          int b = rg >> 11, s = rg & 2047, hd2 = cg >> 6, dd = cg & 63;
          size_t off = ((size_t)((b * 16 + hd2) * 64 + dd)) * 2048 + s;
          oH[off] = f2bf(val);
        } else {
          oF[(size_t)rg * 1024 + cg] = val;
        }
      }
    }
}

// fused Q/K/V projection: grid (32, 24); y: 0-7 Q (split, scaled), 8-15 K (split), 16-23 V (plain, transposed)
__global__ __launch_bounds__(256) void k_qkv(
    const u16* __restrict__ xh, const u16* __restrict__ xl,
    const u16* __restrict__ wqh, const u16* __restrict__ wql,
    const u16* __restrict__ wkh, const u16* __restrict__ wkl,
    const u16* __restrict__ wvb,
    const float* __restrict__ bq, const float* __restrict__ bk,
    const float* __restrict__ bv,
    u16* __restrict__ qh, u16* __restrict__ ql,
    u16* __restrict__ kh, u16* __restrict__ kl, u16* __restrict__ vt) {
  __shared__ u16 sm[16384];
  int which = blockIdx.y >> 3;
  int m0 = blockIdx.x * 128, n0 = (blockIdx.y & 7) * 128;
  if (which == 0)
    gemm_body<1, 0>(sm, xh, xl, wqh, wql, bq, 0.125f * L2E, qh, ql, nullptr, m0, n0);
  else if (which == 1)
    gemm_body<1, 0>(sm, xh, xl, wkh, wkl, bk, 1.0f, kh, kl, nullptr, m0, n0);
  else
    gemm_body<0, 1>(sm, xh, nullptr, wvb, nullptr, bv, 1.0f, vt, nullptr, nullptr, m0, n0);
}

__global__ __launch_bounds__(256) void k_oproj(
    const u16* __restrict__ ao, const u16* __restrict__ wob,
    const float* __restrict__ bo, float* __restrict__ out) {
  __shared__ u16 sm[8192];
  gemm_body<0, 2>(sm, ao, nullptr, wob, nullptr, bo, 1.0f, nullptr, nullptr, out,
                  blockIdx.x * 128, blockIdx.y * 128);
}

// ---------------- flash attention (causal), balanced pairs, swapped-operand softmax ----------------
// Q pre-scaled by 0.125*log2(e) (folded into projection). Scores come out in log2 domain.
// Block = 128 threads (2 waves x 16 q-rows); processes q-tiles j=pr and j=63-pr (33 kv-iters always).
__global__ __launch_bounds__(128) void k_attn(
    const u16* __restrict__ Qh, const u16* __restrict__ Ql,
    const u16* __restrict__ Kh, const u16* __restrict__ Kl,
    const u16* __restrict__ Vt, u16* __restrict__ Oa) {
  __shared__ u16 sKh[4096], sKl[4096], sVt[4096];
  __shared__ u16 sP[2][1024];

  const int tid = threadIdx.x;
  const int lane = tid & 63, w = tid >> 6;
  const int fr = lane & 15, fg = lane >> 4;

  // XCD-chunked mapping: dispatch id d -> XCD d%8 owns bh group (d&7)*4 + (d>>8)
  const int d = blockIdx.y * 32 + blockIdx.x;
  const int bh = (d & 7) * 4 + (d >> 8);
  const int pr = (d >> 3) & 31;

  const size_t base = (size_t)bh * 131072;
  const u16* Qh_p = Qh + base;
  const u16* Ql_p = Ql + base;
  const u16* Kh_p = Kh + base;
  const u16* Kl_p = Kl + base;
  const u16* Vt_p = Vt + base;
  const int bb = bh >> 4, hh = bh & 15;

  const int srow = tid >> 3, scb = tid & 7;

  for (int half = 0; half < 2; ++half) {
    const int j = half ? (63 - pr) : pr;
    const int nt = (j >> 1) + 1;
    const int qrow = j * 32 + w * 16 + fr;

    bf16x8 qhf[2], qlf[2];
#pragma unroll
    for (int ks = 0; ks < 2; ++ks) {
      qhf[ks] = *(const bf16x8*)(Qh_p + (size_t)qrow * 64 + ks * 32 + fg * 8);
      qlf[ks] = *(const bf16x8*)(Ql_p + (size_t)qrow * 64 + ks * 32 + fg * 8);
    }

    float mx = -1e30f, l = 0.f;
    f32x4 o[4];
#pragma unroll
    for (int f = 0; f < 4; ++f) o[f] = fzero();

    for (int t = 0; t < nt; ++t) {
      __syncthreads();
#pragma unroll
      for (int r2 = 0; r2 < 4; ++r2) {
        int row = r2 * 16 + srow;
        int cbs = scb ^ (row & 7);
        gl_lds16(Kh_p + ((size_t)(t * 64 + row)) * 64 + cbs * 8, sKh + row * 64 + scb * 8);
        gl_lds16(Kl_p + ((size_t)(t * 64 + row)) * 64 + cbs * 8, sKl + row * 64 + scb * 8);
        gl_lds16(Vt_p + (size_t)row * 2048 + t * 64 + cbs * 8, sVt + row * 64 + scb * 8);
      }
      __syncthreads();

      // QK^T swapped: A=K (out-row = kv), B=Q (out-col = q). sc[f]: kv = f*16+fg*4+r, q = fr
      f32x4 sc[4];
      __builtin_amdgcn_s_setprio(1);
#pragma unroll
      for (int f = 0; f < 4; ++f) {
        f32x4 a = fzero();
#pragma unroll
        for (int ks = 0; ks < 2; ++ks) {
          int row = f * 16 + fr;
          int cb = (fg + 4 * ks) ^ (row & 7);
          bf16x8 khv = *(const bf16x8*)(sKh + row * 64 + cb * 8);
          bf16x8 klv = *(const bf16x8*)(sKl + row * 64 + cb * 8);
          a = mfma16(khv, qhf[ks], a);
          a = mfma16(khv, qlf[ks], a);
          a = mfma16(klv, qhf[ks], a);
        }
        sc[f] = a;
      }
      __builtin_amdgcn_s_setprio(0);

      if (t == nt - 1) {
#pragma unroll
        for (int f = 0; f < 4; ++f)
#pragma unroll
          for (int r = 0; r < 4; ++r) {
            int kvg = t * 64 + f * 16 + fg * 4 + r;
            if (kvg > qrow) sc[f][r] = -1e30f;
          }
      }

      // online softmax in log2 domain; each thread owns q=fr (replicated x4 across fg)
      float pm = -1e30f;
#pragma unroll
      for (int f = 0; f < 4; ++f)
#pragma unroll
        for (int r = 0; r < 4; ++r) pm = fmaxf(pm, sc[f][r]);
      pm = fmaxf(pm, __shfl_xor(pm, 16, 64));
      pm = fmaxf(pm, __shfl_xor(pm, 32, 64));
      float mn = fmaxf(mx, pm);
      float alp = exp2f(mx - mn);
      mx = mn;

      float ps = 0.f;
#pragma unroll
      for (int f = 0; f < 4; ++f) {
        float p0 = exp2f(sc[f][0] - mx);
        float p1 = exp2f(sc[f][1] - mx);
        float p2 = exp2f(sc[f][2] - mx);
        float p3 = exp2f(sc[f][3] - mx);
        ps += (p0 + p1) + (p2 + p3);
        uint2 pv;
        pv.x = (u32)f2bf(p0) | ((u32)f2bf(p1) << 16);
        pv.y = (u32)f2bf(p2) | ((u32)f2bf(p3) << 16);
        int e = (f * 16 + fg * 4) ^ ((fr & 7) << 3);
        *(uint2*)(&sP[w][fr * 64 + e]) = pv;
      }
      ps += __shfl_xor(ps, 16, 64);
      ps += __shfl_xor(ps, 32, 64);
      l = l * alp + ps;

      float alpb[4];
#pragma unroll
      for (int r = 0; r < 4; ++r) alpb[r] = __shfl(alp, fg * 4 + r, 64);
#pragma unroll
      for (int f = 0; f < 4; ++f)
#pragma unroll
        for (int r = 0; r < 4; ++r) o[f][r] *= alpb[r];

      // PV: A=P (out-row = q), B=V^T (out-col = d). o[f][r] = O[q=fg*4+r][d=f*16+fr]
      __builtin_amdgcn_s_setprio(1);
#pragma unroll
      for (int ks = 0; ks < 2; ++ks) {
        int e = (ks * 32 + fg * 8) ^ ((fr & 7) << 3);
        bf16x8 pa = *(const bf16x8*)(&sP[w][fr * 64 + e]);
#pragma unroll
        for (int f = 0; f < 4; ++f) {
          int row = f * 16 + fr;
          int cb = (fg + 4 * ks) ^ (row & 7);
          bf16x8 vb = *(const bf16x8*)(sVt + row * 64 + cb * 8);
          o[f] = mfma16(pa, vb, o[f]);
        }
      }
      __builtin_amdgcn_s_setprio(0);
    }

    float lb[4];
#pragma unroll
    for (int r = 0; r < 4; ++r) lb[r] = __shfl(l, fg * 4 + r, 64);
#pragma unroll
    for (int f = 0; f < 4; ++f)
#pragma unroll
      for (int r = 0; r < 4; ++r) {
        int qg = j * 32 + w * 16 + fg * 4 + r;
        float val = o[f][r] / lb[r];
        Oa[((size_t)(bb * 2048 + qg)) * 1024 + hh * 64 + f * 16 + fr] = f2bf(val);
      }
  }
}

// ---------------- launcher ----------------
extern "C" void kernel_launch(void* const* d_in, const int* in_sizes, int n_in,
                              void* d_out, int out_size, void* d_ws, size_t ws_size,
                              hipStream_t stream) {
  const float* x  = (const float*)d_in[0];
  const float* Wq = (const float*)d_in[1];
  const float* bq = (const float*)d_in[2];
  const float* Wk = (const float*)d_in[3];
  const float* bk = (const float*)d_in[4];
  const float* Wv = (const float*)d_in[5];
  const float* bv = (const float*)d_in[6];
  const float* Wo = (const float*)d_in[7];
  const float* bo = (const float*)d_in[8];
  float* out = (float*)d_out;

  u16* ws  = (u16*)d_ws;
  u16* xh  = ws;
  u16* xl  = xh + 4194304;
  u16* wqh = xl + 4194304;
  u16* wql = wqh + 1048576;
  u16* wkh = wql + 1048576;
  u16* wkl = wkh + 1048576;
  u16* wvb = wkl + 1048576;
  u16* wob = wvb + 1048576;
  u16* qh  = wob + 1048576;
  u16* ql  = qh + 4194304;
  u16* kh  = ql + 4194304;
  u16* kl  = kh + 4194304;
  u16* vt  = kl + 4194304;
  u16* ao  = xh;  // x_hi dead after projections; reuse for attention output

  k_prep<<<8192, 256, 0, stream>>>(x, Wq, Wk, Wv, Wo, xh, xl, wqh, wql, wkh, wkl, wvb, wob);
  k_qkv<<<dim3(32, 24), 256, 0, stream>>>(xh, xl, wqh, wql, wkh, wkl, wvb, bq, bk, bv,
                                          qh, ql, kh, kl, vt);
  k_attn<<<dim3(32, 32), 128, 0, stream>>>(qh, ql, kh, kl, vt, ao);
  k_oproj<<<dim3(32, 8), 256, 0, stream>>>(ao, wob, bo, out);
}

// Round 3
// 172.967 us; speedup vs baseline: 1.7527x; 1.0900x over previous
//
#include <hip/hip_runtime.h>

typedef unsigned short u16;
typedef unsigned int u32;
typedef __attribute__((ext_vector_type(4))) float f32x4;
typedef __attribute__((ext_vector_type(8))) __bf16 bf16x8;

#define L2E 1.4426950408889634f

__device__ __forceinline__ u16 f2bf(float f) { return __builtin_bit_cast(u16, (__bf16)f); }
__device__ __forceinline__ float bf2f(u16 h) { return (float)__builtin_bit_cast(__bf16, h); }
__device__ __forceinline__ f32x4 mfma16(bf16x8 a, bf16x8 b, f32x4 c) {
  return __builtin_amdgcn_mfma_f32_16x16x32_bf16(a, b, c, 0, 0, 0);
}
__device__ __forceinline__ void gl_lds16(const u16* g, u16* l) {
  __builtin_amdgcn_global_load_lds((__attribute__((address_space(1))) void*)g,
                                   (__attribute__((address_space(3))) void*)l,
                                   16, 0, 0);
}
__device__ __forceinline__ f32x4 fzero() {
  f32x4 v = {0.f, 0.f, 0.f, 0.f};
  return v;
}

// ---------------- fused prep: x hi/lo split, Wq/Wk splits, Wv/Wo converts ----------------
__global__ void k_prep(const float* __restrict__ x, const float* __restrict__ Wq,
                       const float* __restrict__ Wk, const float* __restrict__ Wv,
                       const float* __restrict__ Wo,
                       u16* __restrict__ xh, u16* __restrict__ xl,
                       u16* __restrict__ wqh, u16* __restrict__ wql,
                       u16* __restrict__ wkh, u16* __restrict__ wkl,
                       u16* __restrict__ wvb, u16* __restrict__ wob) {
  int i = (blockIdx.x * 256 + threadIdx.x) * 4;
  const float* src;
  u16* hi;
  u16* lo;
  int j;
  if (i < 4194304)      { src = x;  hi = xh;  lo = xl;      j = i; }
  else if (i < 5242880) { src = Wq; hi = wqh; lo = wql;     j = i - 4194304; }
  else if (i < 6291456) { src = Wk; hi = wkh; lo = wkl;     j = i - 5242880; }
  else if (i < 7340032) { src = Wv; hi = wvb; lo = nullptr; j = i - 6291456; }
  else                  { src = Wo; hi = wob; lo = nullptr; j = i - 7340032; }
  float4 v = *(const float4*)(src + j);
  float vv[4] = {v.x, v.y, v.z, v.w};
  u16 hh[4];
#pragma unroll
  for (int t = 0; t < 4; ++t) hh[t] = f2bf(vv[t]);
  *(ushort4*)(hi + j) = make_ushort4(hh[0], hh[1], hh[2], hh[3]);
  if (lo) {
    u16 ll[4];
#pragma unroll
    for (int t = 0; t < 4; ++t) ll[t] = f2bf(vv[t] - bf2f(hh[t]));
    *(ushort4*)(lo + j) = make_ushort4(ll[0], ll[1], ll[2], ll[3]);
  }
}

// ---------------- GEMM body: C[.][1024] = A[.][1024] * B[1024][1024]^T + bias ----------------
template <int SPLIT, int EPI>
__device__ __forceinline__ void gemm_body(
    u16* sm, const u16* __restrict__ Ah, const u16* __restrict__ Al,
    const u16* __restrict__ Bh, const u16* __restrict__ Bl,
    const float* __restrict__ bias, float scale,
    u16* __restrict__ oH, u16* __restrict__ oL, float* __restrict__ oF,
    int m0, int n0) {
  u16* sAh = sm;
  u16* sBh = sm + 4096;
  u16* sAl = SPLIT ? (sm + 8192) : sm;
  u16* sBl = SPLIT ? (sm + 12288) : sm;

  const int tid = threadIdx.x;
  const int lane = tid & 63, w = tid >> 6;
  const int wm = w >> 1, wn = w & 1;
  const int fr = lane & 15, fg = lane >> 4;
  const int srow = tid >> 2, scb = (tid & 3) * 8;

  f32x4 acc[4][4];
#pragma unroll
  for (int i = 0; i < 4; ++i)
#pragma unroll
    for (int j = 0; j < 4; ++j) acc[i][j] = fzero();

  for (int kk = 0; kk < 1024; kk += 32) {
    __syncthreads();
#pragma unroll
    for (int r = 0; r < 2; ++r) {
      int row = r * 64 + srow;
      gl_lds16(Ah + (size_t)(m0 + row) * 1024 + kk + scb, sAh + row * 32 + scb);
      gl_lds16(Bh + (size_t)(n0 + row) * 1024 + kk + scb, sBh + row * 32 + scb);
      if constexpr (SPLIT) {
        gl_lds16(Al + (size_t)(m0 + row) * 1024 + kk + scb, sAl + row * 32 + scb);
        gl_lds16(Bl + (size_t)(n0 + row) * 1024 + kk + scb, sBl + row * 32 + scb);
      }
    }
    __syncthreads();

    bf16x8 ah[4], bh[4], al[4], bl[4];
#pragma unroll
    for (int i = 0; i < 4; ++i) {
      ah[i] = *(const bf16x8*)(sAh + (wm * 64 + i * 16 + fr) * 32 + fg * 8);
      bh[i] = *(const bf16x8*)(sBh + (wn * 64 + i * 16 + fr) * 32 + fg * 8);
      if constexpr (SPLIT) {
        al[i] = *(const bf16x8*)(sAl + (wm * 64 + i * 16 + fr) * 32 + fg * 8);
        bl[i] = *(const bf16x8*)(sBl + (wn * 64 + i * 16 + fr) * 32 + fg * 8);
      }
    }
#pragma unroll
    for (int i = 0; i < 4; ++i)
#pragma unroll
      for (int j = 0; j < 4; ++j) {
        acc[i][j] = mfma16(ah[i], bh[j], acc[i][j]);
        if constexpr (SPLIT) {
          acc[i][j] = mfma16(ah[i], bl[j], acc[i][j]);
          acc[i][j] = mfma16(al[i], bh[j], acc[i][j]);
        }
      }
  }

  // C/D layout: col = lane&15, row = (lane>>4)*4 + r
#pragma unroll
  for (int i = 0; i < 4; ++i)
#pragma unroll
    for (int j = 0; j < 4; ++j) {
      int cg = n0 + wn * 64 + j * 16 + fr;
      float bv = bias[cg];
#pragma unroll
      for (int r = 0; r < 4; ++r) {
        int rg = m0 + wm * 64 + i * 16 + fg * 4 + r;
        float val = (acc[i][j][r] + bv) * scale;
        if constexpr (EPI == 0) {
          int b = rg >> 11, s = rg & 2047, hd2 = cg >> 6, dd = cg & 63;
          size_t off = ((size_t)((b * 16 + hd2) * 2048 + s)) * 64 + dd;
          u16 hv = f2bf(val);
          oH[off] = hv;
          oL[off] = f2bf(val - bf2f(hv));
        } else if constexpr (EPI == 1) {
          int b = rg >> 11, s = rg & 2047, hd2 = cg >> 6, dd = cg & 63;
          size_t off = ((size_t)((b * 16 + hd2) * 64 + dd)) * 2048 + s;
          oH[off] = f2bf(val);
        } else {
          oF[(size_t)rg * 1024 + cg] = val;
        }
      }
    }
}

__global__ __launch_bounds__(256) void k_qkv(
    const u16* __restrict__ xh, const u16* __restrict__ xl,
    const u16* __restrict__ wqh, const u16* __restrict__ wql,
    const u16* __restrict__ wkh, const u16* __restrict__ wkl,
    const u16* __restrict__ wvb,
    const float* __restrict__ bq, const float* __restrict__ bk,
    const float* __restrict__ bv,
    u16* __restrict__ qh, u16* __restrict__ ql,
    u16* __restrict__ kh, u16* __restrict__ kl, u16* __restrict__ vt) {
  __shared__ u16 sm[16384];
  int which = blockIdx.y >> 3;
  int m0 = blockIdx.x * 128, n0 = (blockIdx.y & 7) * 128;
  if (which == 0)
    gemm_body<1, 0>(sm, xh, xl, wqh, wql, bq, 0.125f * L2E, qh, ql, nullptr, m0, n0);
  else if (which == 1)
    gemm_body<1, 0>(sm, xh, xl, wkh, wkl, bk, 1.0f, kh, kl, nullptr, m0, n0);
  else
    gemm_body<0, 1>(sm, xh, nullptr, wvb, nullptr, bv, 1.0f, vt, nullptr, nullptr, m0, n0);
}

__global__ __launch_bounds__(256) void k_oproj(
    const u16* __restrict__ ao, const u16* __restrict__ wob,
    const float* __restrict__ bo, float* __restrict__ out) {
  __shared__ u16 sm[8192];
  gemm_body<0, 2>(sm, ao, nullptr, wob, nullptr, bo, 1.0f, nullptr, nullptr, out,
                  blockIdx.x * 128, blockIdx.y * 128);
}

// ---------------- flash attention (causal) ----------------
// 256 threads = 4 waves, QBLK=64 (wave w owns rows w*16..w*16+15 of the tile).
// Pair-balanced: block handles q-tiles j=pr and 31-pr -> 33 kv-iters always.
// Double-buffered K/V staging with counted vmcnt + raw barriers (T3/T4 minimum).
// Q pre-scaled by 0.125*log2(e); softmax in log2 domain; swapped QK^T (q = lane&15).
__global__ __launch_bounds__(256) void k_attn(
    const u16* __restrict__ Qh, const u16* __restrict__ Ql,
    const u16* __restrict__ Kh, const u16* __restrict__ Kl,
    const u16* __restrict__ Vt, u16* __restrict__ Oa) {
  __shared__ u16 sKh[2][4096], sKl[2][4096], sVt[2][4096];  // 48 KB
  __shared__ u16 sP[4][1024];                                // 8 KB

  const int tid = threadIdx.x;
  const int lane = tid & 63, w = tid >> 6;
  const int fr = lane & 15, fg = lane >> 4;

  // XCD-chunked: xcd = d&7 owns bh = (d&7)*4 + (d>>7); K/V for 4 bh = 3 MB -> one L2
  const int d = blockIdx.x;
  const int bh = (d & 7) * 4 + (d >> 7);
  const int pr = (d >> 3) & 15;

  const size_t base = (size_t)bh * 131072;
  const u16* Qh_p = Qh + base;
  const u16* Ql_p = Ql + base;
  const u16* Kh_p = Kh + base;
  const u16* Kl_p = Kl + base;
  const u16* Vt_p = Vt + base;
  const int bb = bh >> 4, hh = bh & 15;

  const int srow8 = tid >> 3, scb8 = tid & 7;

  auto STAGE = [&](int t, int c) {
#pragma unroll
    for (int r2 = 0; r2 < 2; ++r2) {
      int row = r2 * 32 + srow8;
      int cbs = scb8 ^ (row & 7);
      gl_lds16(Kh_p + ((size_t)(t * 64 + row)) * 64 + cbs * 8, &sKh[c][row * 64 + scb8 * 8]);
      gl_lds16(Kl_p + ((size_t)(t * 64 + row)) * 64 + cbs * 8, &sKl[c][row * 64 + scb8 * 8]);
      gl_lds16(Vt_p + (size_t)row * 2048 + t * 64 + cbs * 8, &sVt[c][row * 64 + scb8 * 8]);
    }
  };

  for (int half = 0; half < 2; ++half) {
    const int j = half ? (31 - pr) : pr;
    const int nt = j + 1;
    const int qrow = j * 64 + w * 16 + fr;

    bf16x8 qhf[2], qlf[2];
#pragma unroll
    for (int ks = 0; ks < 2; ++ks) {
      qhf[ks] = *(const bf16x8*)(Qh_p + (size_t)qrow * 64 + ks * 32 + fg * 8);
      qlf[ks] = *(const bf16x8*)(Ql_p + (size_t)qrow * 64 + ks * 32 + fg * 8);
    }

    float mx = -1e30f, l = 0.f;
    f32x4 o[4];
#pragma unroll
    for (int f = 0; f < 4; ++f) o[f] = fzero();

    STAGE(0, 0);

    for (int t = 0; t < nt; ++t) {
      const int cur = t & 1;
      if (t + 1 < nt) {
        STAGE(t + 1, cur ^ 1);                           // prefetch next tile
        asm volatile("s_waitcnt vmcnt(6)" ::: "memory"); // current tile's 6 loads done
      } else {
        asm volatile("s_waitcnt vmcnt(0)" ::: "memory");
      }
      asm volatile("s_barrier" ::: "memory");

      const u16* kbh = sKh[cur];
      const u16* kbl = sKl[cur];
      const u16* vbb = sVt[cur];

      // QK^T swapped: A=K, B=Q. sc[f]: kv = f*16+fg*4+r, q = fr
      f32x4 sc[4];
      __builtin_amdgcn_s_setprio(1);
#pragma unroll
      for (int f = 0; f < 4; ++f) {
        f32x4 a = fzero();
#pragma unroll
        for (int ks = 0; ks < 2; ++ks) {
          int row = f * 16 + fr;
          int cb = (fg + 4 * ks) ^ (fr & 7);
          bf16x8 khv = *(const bf16x8*)(kbh + row * 64 + cb * 8);
          bf16x8 klv = *(const bf16x8*)(kbl + row * 64 + cb * 8);
          a = mfma16(khv, qhf[ks], a);
          a = mfma16(khv, qlf[ks], a);
          a = mfma16(klv, qhf[ks], a);
        }
        sc[f] = a;
      }
      __builtin_amdgcn_s_setprio(0);

      if (t == nt - 1) {
#pragma unroll
        for (int f = 0; f < 4; ++f)
#pragma unroll
          for (int r = 0; r < 4; ++r) {
            int kvg = t * 64 + f * 16 + fg * 4 + r;
            if (kvg > qrow) sc[f][r] = -1e30f;
          }
      }

      // online softmax (log2 domain), defer-max (T13): skip rescale if max grew < 2^11.5
      float pm = -1e30f;
#pragma unroll
      for (int f = 0; f < 4; ++f)
#pragma unroll
        for (int r = 0; r < 4; ++r) pm = fmaxf(pm, sc[f][r]);
      pm = fmaxf(pm, __shfl_xor(pm, 16, 64));
      pm = fmaxf(pm, __shfl_xor(pm, 32, 64));

      const bool resc = __any(pm > mx + 11.5f);
      float alp = 1.0f;
      if (resc) {
        float mn = fmaxf(mx, pm);
        alp = exp2f(mx - mn);
        mx = mn;
      }

      float ps = 0.f;
#pragma unroll
      for (int f = 0; f < 4; ++f) {
        float p0 = exp2f(sc[f][0] - mx);
        float p1 = exp2f(sc[f][1] - mx);
        float p2 = exp2f(sc[f][2] - mx);
        float p3 = exp2f(sc[f][3] - mx);
        ps += (p0 + p1) + (p2 + p3);
        uint2 pv;
        pv.x = (u32)f2bf(p0) | ((u32)f2bf(p1) << 16);
        pv.y = (u32)f2bf(p2) | ((u32)f2bf(p3) << 16);
        int e = (f * 16 + fg * 4) ^ ((fr & 7) << 3);
        *(uint2*)(&sP[w][fr * 64 + e]) = pv;
      }
      ps += __shfl_xor(ps, 16, 64);
      ps += __shfl_xor(ps, 32, 64);
      l = l * alp + ps;

      if (resc) {
        float alpb[4];
#pragma unroll
        for (int r = 0; r < 4; ++r) alpb[r] = __shfl(alp, fg * 4 + r, 64);
#pragma unroll
        for (int f = 0; f < 4; ++f)
#pragma unroll
          for (int r = 0; r < 4; ++r) o[f][r] *= alpb[r];
      }

      // PV: A=P (row=q), B=V^T (col=d). o[f][r] = O[q=fg*4+r][d=f*16+fr]
      __builtin_amdgcn_s_setprio(1);
#pragma unroll
      for (int ks = 0; ks < 2; ++ks) {
        int e = (ks * 32 + fg * 8) ^ ((fr & 7) << 3);
        bf16x8 pa = *(const bf16x8*)(&sP[w][fr * 64 + e]);
#pragma unroll
        for (int f = 0; f < 4; ++f) {
          int row = f * 16 + fr;
          int cb = (fg + 4 * ks) ^ (fr & 7);
          bf16x8 vb = *(const bf16x8*)(vbb + row * 64 + cb * 8);
          o[f] = mfma16(pa, vb, o[f]);
        }
      }
      __builtin_amdgcn_s_setprio(0);

      asm volatile("s_barrier" ::: "memory");  // all reads of buf[cur] done before restage
    }

    float lb[4];
#pragma unroll
    for (int r = 0; r < 4; ++r) lb[r] = __shfl(l, fg * 4 + r, 64);
#pragma unroll
    for (int f = 0; f < 4; ++f)
#pragma unroll
      for (int r = 0; r < 4; ++r) {
        int qg = j * 64 + w * 16 + fg * 4 + r;
        float val = o[f][r] / lb[r];
        Oa[((size_t)(bb * 2048 + qg)) * 1024 + hh * 64 + f * 16 + fr] = f2bf(val);
      }
  }
}

// ---------------- launcher ----------------
extern "C" void kernel_launch(void* const* d_in, const int* in_sizes, int n_in,
                              void* d_out, int out_size, void* d_ws, size_t ws_size,
                              hipStream_t stream) {
  const float* x  = (const float*)d_in[0];
  const float* Wq = (const float*)d_in[1];
  const float* bq = (const float*)d_in[2];
  const float* Wk = (const float*)d_in[3];
  const float* bk = (const float*)d_in[4];
  const float* Wv = (const float*)d_in[5];
  const float* bv = (const float*)d_in[6];
  const float* Wo = (const float*)d_in[7];
  const float* bo = (const float*)d_in[8];
  float* out = (float*)d_out;

  u16* ws  = (u16*)d_ws;
  u16* xh  = ws;
  u16* xl  = xh + 4194304;
  u16* wqh = xl + 4194304;
  u16* wql = wqh + 1048576;
  u16* wkh = wql + 1048576;
  u16* wkl = wkh + 1048576;
  u16* wvb = wkl + 1048576;
  u16* wob = wvb + 1048576;
  u16* qh  = wob + 1048576;
  u16* ql  = qh + 4194304;
  u16* kh  = ql + 4194304;
  u16* kl  = kh + 4194304;
  u16* vt  = kl + 4194304;
  u16* ao  = xh;  // x_hi dead after projections; reuse for attention output

  k_prep<<<8192, 256, 0, stream>>>(x, Wq, Wk, Wv, Wo, xh, xl, wqh, wql, wkh, wkl, wvb, wob);
  k_qkv<<<dim3(32, 24), 256, 0, stream>>>(xh, xl, wqh, wql, wkh, wkl, wvb, bq, bk, bv,
                                          qh, ql, kh, kl, vt);
  k_attn<<<512, 256, 0, stream>>>(qh, ql, kh, kl, vt, ao);
  k_oproj<<<dim3(32, 8), 256, 0, stream>>>(ao, wob, bo, out);
}